// Round 11
// baseline (270.749 us; speedup 1.0000x reference)
//
#include <hip/hip_runtime.h>
#include <math.h>

// ---------------------------------------------------------------------------
// BasicTransBlock: BN1 -> dw3x3x3 -> pw(C->3C) -> attn(K/V downsampled to 8^3,
// rel-pos bias) -> dw3x3x3 -> pw(C->C) -> +x -> BN2 -> ReLU -> 1x1x1 -> +res
// bf16 MFMA for attention AND all pointwise GEMMs (fp32 accum everywhere).
// ---------------------------------------------------------------------------

typedef short bf16x8 __attribute__((ext_vector_type(8)));
typedef float f32x4 __attribute__((ext_vector_type(4)));
typedef unsigned short u16x8 __attribute__((ext_vector_type(8)));

constexpr int CNUM  = 128;
constexpr int NSP   = 32768;      // 32*32*32
constexpr int HEADS = 4;
constexpr int M3    = 512;        // 8^3
constexpr float EPSV  = 1e-5f;
constexpr float SCALE = 0.17677669529663688f;   // 32^-0.5
constexpr float SK    = SCALE * 1.44269504088896340736f;  // *log2(e)

// workspace layout (float slots). Aliasing audit (R6) unchanged.
constexpr size_t F_HDW16 = 0;
constexpr size_t F_HDWT  = 2097152;
constexpr size_t F_QKV   = 4194304;
constexpr size_t F_ATTN  = 0;                   // fp32 [0,4M)
constexpr size_t F_TMP2  = F_QKV;               // bf16, 2M slots
constexpr size_t F_TMP2T = F_QKV + 2097152;     // bf16, 2M slots
constexpr size_t F_Y1    = F_QKV + 4194304;     // fp32, 4M slots
constexpr size_t F_Y1T   = F_QKV + 8388608;     // bf16, 2M slots
constexpr size_t F_KD    = 16777216;            // ushort[4*512*32]  = 32768 slots
constexpr size_t F_VT    = F_KD + 32768;        // ushort[4*32*512]  = 32768 slots
constexpr size_t F_BIAS  = F_VT + 32768;        // ushort[4*512*512] = 524288 slots
constexpr size_t F_ST    = F_BIAS + 524288;     // 512 floats

__device__ inline ushort f2bf(float f) {
  unsigned u = __float_as_uint(f);
  u += 0x7fff + ((u >> 16) & 1);
  return (ushort)(u >> 16);
}
__device__ inline float bf2f(ushort u) { return __uint_as_float(((unsigned)u) << 16); }

// ---------------- BN stats: per-channel scale/shift ------------------------
__global__ __launch_bounds__(256) void bn_stats(
    const float* __restrict__ x, const float* __restrict__ g,
    const float* __restrict__ bb, float* __restrict__ scale,
    float* __restrict__ shift) {
  const int c = blockIdx.x;
  const float4* p = (const float4*)(x + (size_t)c * NSP);
  float s = 0.f, s2 = 0.f;
  for (int i = threadIdx.x; i < NSP / 4; i += 256) {
    float4 v = p[i];
    s  += v.x + v.y + v.z + v.w;
    s2 += v.x * v.x + v.y * v.y + v.z * v.z + v.w * v.w;
  }
  __shared__ float rs[4], rs2[4];
  for (int off = 32; off > 0; off >>= 1) {
    s  += __shfl_down(s, off);
    s2 += __shfl_down(s2, off);
  }
  if ((threadIdx.x & 63) == 0) { rs[threadIdx.x >> 6] = s; rs2[threadIdx.x >> 6] = s2; }
  __syncthreads();
  if (threadIdx.x == 0) {
    float S = rs[0] + rs[1] + rs[2] + rs[3];
    float S2 = rs2[0] + rs2[1] + rs2[2] + rs2[3];
    float mu = S / (float)NSP;
    float var = S2 / (float)NSP - mu * mu;
    float sc = g[c] * rsqrtf(var + EPSV);
    scale[c] = sc;
    shift[c] = bb[c] - mu * sc;
  }
}

// ---------------- depthwise 3x3x3 conv, register-blocked, bf16 out ---------
template <bool AFFINE>
__global__ __launch_bounds__(256) void dwconv3(
    const float* __restrict__ in, const float* __restrict__ w27,
    const float* __restrict__ scale, const float* __restrict__ shift,
    ushort* __restrict__ out) {
  const int idx = blockIdx.x * 256 + threadIdx.x;
  const int d0 = (idx & 3) << 3;
  const int ww = (idx >> 2) & 31;
  const int hh = (idx >> 7) & 31;
  const int c  = idx >> 12;
  const float sc = AFFINE ? scale[c] : 1.f;
  const float sh = AFFINE ? shift[c] : 0.f;
  const float* pc = in + ((size_t)c << 15);
  const float* wc = w27 + c * 27;
  float wreg[27];
#pragma unroll
  for (int k = 0; k < 27; ++k) wreg[k] = wc[k];

  float acc[8] = {};
#pragma unroll
  for (int a = 0; a < 3; ++a) {
    int h2 = hh + a - 1;
    if ((unsigned)h2 > 31u) continue;
#pragma unroll
    for (int b = 0; b < 3; ++b) {
      int w2 = ww + b - 1;
      if ((unsigned)w2 > 31u) continue;
      const float* row = pc + (h2 << 10) + (w2 << 5) + d0;
      float4 v0 = *(const float4*)(row);
      float4 v1 = *(const float4*)(row + 4);
      float win[10];
      if (AFFINE) {
        win[1] = fmaf(v0.x, sc, sh); win[2] = fmaf(v0.y, sc, sh);
        win[3] = fmaf(v0.z, sc, sh); win[4] = fmaf(v0.w, sc, sh);
        win[5] = fmaf(v1.x, sc, sh); win[6] = fmaf(v1.y, sc, sh);
        win[7] = fmaf(v1.z, sc, sh); win[8] = fmaf(v1.w, sc, sh);
        win[0] = (d0 > 0)  ? fmaf(row[-1], sc, sh) : 0.f;
        win[9] = (d0 < 24) ? fmaf(row[8],  sc, sh) : 0.f;
      } else {
        win[1] = v0.x; win[2] = v0.y; win[3] = v0.z; win[4] = v0.w;
        win[5] = v1.x; win[6] = v1.y; win[7] = v1.z; win[8] = v1.w;
        win[0] = (d0 > 0)  ? row[-1] : 0.f;
        win[9] = (d0 < 24) ? row[8]  : 0.f;
      }
      const float w0 = wreg[(a * 3 + b) * 3 + 0];
      const float w1 = wreg[(a * 3 + b) * 3 + 1];
      const float w2v = wreg[(a * 3 + b) * 3 + 2];
#pragma unroll
      for (int j = 0; j < 8; ++j)
        acc[j] += w0 * win[j] + w1 * win[j + 1] + w2v * win[j + 2];
    }
  }
  u16x8 o;
#pragma unroll
  for (int j = 0; j < 8; ++j) o[j] = f2bf(acc[j]);
  *(u16x8*)(out + ((size_t)c << 15) + (hh << 10) + (ww << 5) + d0) = o;
}

// ---------------- transpose [c][n] -> [n][c] bf16 (64x64 LDS tiles) --------
template <int MODE>
__global__ __launch_bounds__(256) void transpose_cn(
    const void* __restrict__ inp, const float* __restrict__ sc_,
    const float* __restrict__ sh_, ushort* __restrict__ outp) {
  __shared__ ushort T[64][72];
  const int tid = threadIdx.x;
  const int c0 = (blockIdx.x & 1) << 6;
  const int n0 = (blockIdx.x >> 1) << 6;
  const int r = tid >> 2, q = (tid & 3) << 4;
  if (MODE == 0) {
    const ushort* src = (const ushort*)inp + (size_t)(c0 + r) * NSP + n0 + q;
    *(u16x8*)&T[r][q]     = *(const u16x8*)src;
    *(u16x8*)&T[r][q + 8] = *(const u16x8*)(src + 8);
  } else {
    const float* src = (const float*)inp + (size_t)(c0 + r) * NSP + n0 + q;
    const float s = sc_[c0 + r], h = sh_[c0 + r];
    float4 v0 = ((const float4*)src)[0], v1 = ((const float4*)src)[1];
    float4 v2 = ((const float4*)src)[2], v3 = ((const float4*)src)[3];
    u16x8 a, b;
    a[0] = f2bf(fmaxf(fmaf(v0.x, s, h), 0.f));
    a[1] = f2bf(fmaxf(fmaf(v0.y, s, h), 0.f));
    a[2] = f2bf(fmaxf(fmaf(v0.z, s, h), 0.f));
    a[3] = f2bf(fmaxf(fmaf(v0.w, s, h), 0.f));
    a[4] = f2bf(fmaxf(fmaf(v1.x, s, h), 0.f));
    a[5] = f2bf(fmaxf(fmaf(v1.y, s, h), 0.f));
    a[6] = f2bf(fmaxf(fmaf(v1.z, s, h), 0.f));
    a[7] = f2bf(fmaxf(fmaf(v1.w, s, h), 0.f));
    b[0] = f2bf(fmaxf(fmaf(v2.x, s, h), 0.f));
    b[1] = f2bf(fmaxf(fmaf(v2.y, s, h), 0.f));
    b[2] = f2bf(fmaxf(fmaf(v2.z, s, h), 0.f));
    b[3] = f2bf(fmaxf(fmaf(v2.w, s, h), 0.f));
    b[4] = f2bf(fmaxf(fmaf(v3.x, s, h), 0.f));
    b[5] = f2bf(fmaxf(fmaf(v3.y, s, h), 0.f));
    b[6] = f2bf(fmaxf(fmaf(v3.z, s, h), 0.f));
    b[7] = f2bf(fmaxf(fmaf(v3.w, s, h), 0.f));
    *(u16x8*)&T[r][q]     = a;
    *(u16x8*)&T[r][q + 8] = b;
  }
  __syncthreads();
  const int rn = tid >> 2, cq = (tid & 3) << 4;
  u16x8 o0, o1;
#pragma unroll
  for (int j = 0; j < 8; ++j) { o0[j] = T[cq + j][rn]; o1[j] = T[cq + 8 + j][rn]; }
  ushort* dst = outp + (size_t)(n0 + rn) * 128 + c0 + cq;
  *(u16x8*)dst       = o0;
  *(u16x8*)(dst + 8) = o1;
}

// ---------------- bf16 MFMA GEMM (unchanged from R6) -----------------------
template <bool RES>
__global__ __launch_bounds__(256) void gemm_mfma(
    const float* __restrict__ W, const ushort* __restrict__ Bt,
    const float* __restrict__ res, float* __restrict__ out) {
  __shared__ ushort Wl[128][40];
  __shared__ ushort Bl[128][40];
  const int tid = threadIdx.x;
  const int lane = tid & 63, w = tid >> 6;
  const int g = lane >> 4, c = lane & 15;
  const int n0 = blockIdx.x << 7, oc0 = blockIdx.y << 7;
  const int wr = (w >> 1) << 6, wc = (w & 1) << 6;
  f32x4 acc[4][4];
#pragma unroll
  for (int mt = 0; mt < 4; ++mt)
#pragma unroll
    for (int nt = 0; nt < 4; ++nt) acc[mt][nt] = {0.f, 0.f, 0.f, 0.f};
  const int sr = tid >> 1, sh2 = (tid & 1) << 4;
  for (int k0 = 0; k0 < 128; k0 += 32) {
    __syncthreads();
    {
      const float* wsrc = W + (size_t)(oc0 + sr) * 128 + k0 + sh2;
      float4 a = ((const float4*)wsrc)[0];
      float4 b = ((const float4*)wsrc)[1];
      float4 cc = ((const float4*)wsrc)[2];
      float4 dd = ((const float4*)wsrc)[3];
      u16x8 p0, p1;
      p0[0] = f2bf(a.x);  p0[1] = f2bf(a.y);  p0[2] = f2bf(a.z);  p0[3] = f2bf(a.w);
      p0[4] = f2bf(b.x);  p0[5] = f2bf(b.y);  p0[6] = f2bf(b.z);  p0[7] = f2bf(b.w);
      p1[0] = f2bf(cc.x); p1[1] = f2bf(cc.y); p1[2] = f2bf(cc.z); p1[3] = f2bf(cc.w);
      p1[4] = f2bf(dd.x); p1[5] = f2bf(dd.y); p1[6] = f2bf(dd.z); p1[7] = f2bf(dd.w);
      *(u16x8*)&Wl[sr][sh2]     = p0;
      *(u16x8*)&Wl[sr][sh2 + 8] = p1;
      const ushort* bsrc = Bt + (size_t)(n0 + sr) * 128 + k0 + sh2;
      *(u16x8*)&Bl[sr][sh2]     = *(const u16x8*)bsrc;
      *(u16x8*)&Bl[sr][sh2 + 8] = *(const u16x8*)(bsrc + 8);
    }
    __syncthreads();
    bf16x8 af[4], bfr[4];
#pragma unroll
    for (int mt = 0; mt < 4; ++mt)
      af[mt] = *(const bf16x8*)&Wl[wr + mt * 16 + c][g * 8];
#pragma unroll
    for (int nt = 0; nt < 4; ++nt)
      bfr[nt] = *(const bf16x8*)&Bl[wc + nt * 16 + c][g * 8];
#pragma unroll
    for (int mt = 0; mt < 4; ++mt)
#pragma unroll
      for (int nt = 0; nt < 4; ++nt)
        acc[mt][nt] = __builtin_amdgcn_mfma_f32_16x16x32_bf16(
            af[mt], bfr[nt], acc[mt][nt], 0, 0, 0);
  }
#pragma unroll
  for (int mt = 0; mt < 4; ++mt) {
#pragma unroll
    for (int nt = 0; nt < 4; ++nt) {
      const int n = n0 + wc + nt * 16 + c;
#pragma unroll
      for (int r = 0; r < 4; ++r) {
        const int oc = oc0 + wr + mt * 16 + g * 4 + r;
        size_t off = (size_t)oc * NSP + n;
        float o = acc[mt][nt][r];
        if (RES) o += res[off];
        out[off] = o;
      }
    }
  }
}

// ---------------- trilinear downsample of k,v to 8^3 (bf16 out) ------------
__device__ inline void interp8(int p, int& lo, float& w) {
  double pos = (double)p * 31.0 / 7.0;
  int l = (int)pos;
  if (l > 30) l = 30;
  lo = l;
  w = (float)(pos - (double)l);
}

__global__ __launch_bounds__(128) void downsample_kv(
    const float* __restrict__ qkv, ushort* __restrict__ kd,
    ushort* __restrict__ vt) {
  const int m = blockIdx.x, c = threadIdx.x;
  const int p = m >> 6, q = (m >> 3) & 7, r = m & 7;
  int lp, lq, lr; float wp, wq, wr;
  interp8(p, lp, wp); interp8(q, lq, wq); interp8(r, lr, wr);
  const float* kp = qkv + (size_t)(CNUM + c) * NSP;
  const float* vp = qkv + (size_t)(2 * CNUM + c) * NSP;
  float ak = 0.f, av = 0.f;
#pragma unroll
  for (int a = 0; a < 2; ++a)
#pragma unroll
    for (int b = 0; b < 2; ++b)
#pragma unroll
      for (int e = 0; e < 2; ++e) {
        float wgt = (a ? wp : 1.f - wp) * (b ? wq : 1.f - wq) * (e ? wr : 1.f - wr);
        int off = ((lp + a) << 10) + ((lq + b) << 5) + (lr + e);
        ak = fmaf(wgt, kp[off], ak);
        av = fmaf(wgt, vp[off], av);
      }
  const int d = c >> 2, h = c & 3;
  kd[((size_t)(h * M3 + m)) * 32 + d] = f2bf(ak);       // K: [h][m][d]
  vt[((size_t)(h * 32 + d)) * M3 + m] = f2bf(av);       // V^T: [h][d][m]
}

// ---------------- relative position bias table [4][512][512] bf16 ----------
// R8 change: PRE-SCALED by SK so attention's inner loop is a single fma.
__global__ __launch_bounds__(256) void build_bias(
    const float* __restrict__ rel, ushort* __restrict__ biasmat) {
  const int nr = blockIdx.x;
  const int p0 = nr >> 6, q0 = (nr >> 3) & 7, r0 = nr & 7;
  for (int m = threadIdx.x; m < M3; m += 256) {
    int p1 = m >> 6, q1 = (m >> 3) & 7, r1 = m & 7;
    int idx = (p0 - p1 + 7) * 15 + (q0 - q1 + 7) + (r0 - r1);
    if (idx < 0) idx += 3375;  // torch-style negative wrap
#pragma unroll
    for (int h = 0; h < 4; ++h)
      biasmat[((size_t)(h * M3 + nr)) * M3 + m] = f2bf(rel[idx * 4 + h] * SK);
  }
}

// ---------------- attention: bf16 MFMA, swapped QK^T, online softmax -------
// R8 rework: (1) bias pre-scaled -> inner loop 1 fma; (2) P packed with
// v_cvt_pk_bf16_f32; (3) per-wave P shrunk to [16][40], exp+pack+PV per
// 32-key slice (same-wave DS ordering, no barrier); (4) LDS 62->32KB so
// 4 blocks/CU; (5) setprio around MFMA clusters. Epilogue Ol overlays K/V.
__global__ __launch_bounds__(256, 4) void attention_mfma(
    const float* __restrict__ q, const ushort* __restrict__ kd,
    const ushort* __restrict__ vt, const ushort* __restrict__ biasg,
    float* __restrict__ attn_out) {
  __shared__ ushort lds[16192];
  ushort* Kl = lds;                      // [128][40]
  ushort* Vl = lds + 5120;               // [32][136]
  ushort* Bl = lds + 9472;               // [8][520]  (pre-scaled bias)
  ushort* Pl = lds + 13632;              // 4 waves x [16][40]
  const int tid = threadIdx.x;
  const int lane = tid & 63, w = tid >> 6;
  const int g = lane >> 4, c = lane & 15;
  const int head = blockIdx.x >> 8;
  const int n0 = (blockIdx.x & 255) << 7;

  {  // stage the 8 bias rows (nr varies only in d/4 within this block)
    int nr_base = ((n0 >> 12) << 6) + ((((n0 >> 5) & 31) >> 2) << 3);
    int row = tid >> 5, col = (tid & 31) << 4;
    const float4* src =
        (const float4*)(biasg + ((size_t)(head * M3 + nr_base + row)) * M3 + col);
    *(float4*)&Bl[row * 520 + col] = src[0];
    *(float4*)&Bl[row * 520 + col + 8] = src[1];
  }

  bf16x8 qf[2];
#pragma unroll
  for (int s = 0; s < 2; ++s) {
    int n = n0 + w * 32 + s * 16 + c;
#pragma unroll
    for (int j = 0; j < 8; ++j)
      qf[s][j] = (short)f2bf(q[(size_t)((g * 8 + j) * 4 + head) * NSP + n]);
  }

  f32x4 acc[2][2];
#pragma unroll
  for (int s = 0; s < 2; ++s)
#pragma unroll
    for (int dt = 0; dt < 2; ++dt) acc[s][dt] = {0.f, 0.f, 0.f, 0.f};
  float rmax[2] = {-1e30f, -1e30f};
  float rsum[2] = {0.f, 0.f};
  ushort* Pw = Pl + w * 640;             // [16][40] per wave
  const f32x4 zero4 = {0.f, 0.f, 0.f, 0.f};

  for (int mt = 0; mt < M3; mt += 128) {
    __syncthreads();
    {  // stage K [128][32]->[128][40]; V^T [32][128]->[32][136]
      int r = tid >> 1, hp = (tid & 1) << 4;
      const float4* ksrc =
          (const float4*)(kd + ((size_t)(head * M3 + mt + r)) * 32 + hp);
      *(float4*)&Kl[r * 40 + hp] = ksrc[0];
      *(float4*)&Kl[r * 40 + hp + 8] = ksrc[1];
      int d = tid >> 3, mc = (tid & 7) << 4;
      const float4* vs = (const float4*)(vt + ((size_t)(head * 32 + d)) * M3 + mt + mc);
      *(float4*)&Vl[d * 136 + mc] = vs[0];
      *(float4*)&Vl[d * 136 + mc + 8] = vs[1];
    }
    __syncthreads();
    // S^T = K . Q^T : lane holds col n=c, rows m = 16t + 4g + reg
    f32x4 st[2][8];
    __builtin_amdgcn_s_setprio(1);
#pragma unroll
    for (int t = 0; t < 8; ++t) {
      bf16x8 kf = *(const bf16x8*)&Kl[(t * 16 + c) * 40 + g * 8];
      st[0][t] = __builtin_amdgcn_mfma_f32_16x16x32_bf16(kf, qf[0], zero4, 0, 0, 0);
      st[1][t] = __builtin_amdgcn_mfma_f32_16x16x32_bf16(kf, qf[1], zero4, 0, 0, 0);
    }
    __builtin_amdgcn_s_setprio(0);
#pragma unroll
    for (int s = 0; s < 2; ++s) {
      const int brow = s * 4 + (c >> 2);
      float mx = -1e30f;
#pragma unroll
      for (int t = 0; t < 8; ++t) {
        ushort4 bb = *(const ushort4*)&Bl[brow * 520 + mt + t * 16 + g * 4];
        st[s][t][0] = fmaf(st[s][t][0], SK, bf2f(bb.x));
        st[s][t][1] = fmaf(st[s][t][1], SK, bf2f(bb.y));
        st[s][t][2] = fmaf(st[s][t][2], SK, bf2f(bb.z));
        st[s][t][3] = fmaf(st[s][t][3], SK, bf2f(bb.w));
        mx = fmaxf(mx, fmaxf(fmaxf(st[s][t][0], st[s][t][1]),
                             fmaxf(st[s][t][2], st[s][t][3])));
      }
      mx = fmaxf(mx, __shfl_xor(mx, 16));
      mx = fmaxf(mx, __shfl_xor(mx, 32));
      float mnew = fmaxf(rmax[s], mx);
      float f = exp2f(rmax[s] - mnew);
      rmax[s] = mnew;
      float fr0 = __shfl(f, g * 4 + 0), fr1 = __shfl(f, g * 4 + 1);
      float fr2 = __shfl(f, g * 4 + 2), fr3 = __shfl(f, g * 4 + 3);
#pragma unroll
      for (int dt = 0; dt < 2; ++dt) {
        acc[s][dt][0] *= fr0; acc[s][dt][1] *= fr1;
        acc[s][dt][2] *= fr2; acc[s][dt][3] *= fr3;
      }
      float psum = 0.f;
#pragma unroll
      for (int ks = 0; ks < 4; ++ks) {
        // exp + pack 2 column-groups (32 keys), then PV that slice.
#pragma unroll
        for (int dt2 = 0; dt2 < 2; ++dt2) {
          const int t = ks * 2 + dt2;
          float p0 = exp2f(st[s][t][0] - mnew);
          float p1 = exp2f(st[s][t][1] - mnew);
          float p2 = exp2f(st[s][t][2] - mnew);
          float p3 = exp2f(st[s][t][3] - mnew);
          psum += (p0 + p1) + (p2 + p3);
          unsigned lo, hi;
          asm("v_cvt_pk_bf16_f32 %0, %1, %2" : "=v"(lo) : "v"(p0), "v"(p1));
          asm("v_cvt_pk_bf16_f32 %0, %1, %2" : "=v"(hi) : "v"(p2), "v"(p3));
          uint2 pk; pk.x = lo; pk.y = hi;
          *(uint2*)&Pw[c * 40 + dt2 * 16 + g * 4] = pk;
        }
        // same-wave DS ops are ordered: read back the slice as A-fragment
        bf16x8 pa = *(const bf16x8*)&Pw[c * 40 + g * 8];
        __builtin_amdgcn_s_setprio(1);
#pragma unroll
        for (int dt = 0; dt < 2; ++dt) {
          bf16x8 vb = *(const bf16x8*)&Vl[(dt * 16 + c) * 136 + ks * 32 + g * 8];
          acc[s][dt] = __builtin_amdgcn_mfma_f32_16x16x32_bf16(pa, vb, acc[s][dt], 0, 0, 0);
        }
        __builtin_amdgcn_s_setprio(0);
      }
      psum += __shfl_xor(psum, 16);
      psum += __shfl_xor(psum, 32);
      rsum[s] = rsum[s] * f + psum;
    }
  }
  __syncthreads();              // K/V/bias dead; reuse lds as Ol [128][33] f32
  float* Ol = (float*)lds;
#pragma unroll
  for (int s = 0; s < 2; ++s) {
    float inv = 1.f / rsum[s];
#pragma unroll
    for (int r = 0; r < 4; ++r) {
      float fr = __shfl(inv, g * 4 + r);
      int row = w * 32 + s * 16 + g * 4 + r;
#pragma unroll
      for (int dt = 0; dt < 2; ++dt)
        Ol[row * 33 + dt * 16 + c] = acc[s][dt][r] * fr;
    }
  }
  __syncthreads();
  {
    int d = tid >> 3, seg = tid & 7;
    float vals[16];
#pragma unroll
    for (int i = 0; i < 16; ++i) vals[i] = Ol[(seg * 16 + i) * 33 + d];
    float* dst = attn_out + (size_t)(d * 4 + head) * NSP + n0 + seg * 16;
#pragma unroll
    for (int i = 0; i < 4; ++i) *(float4*)(dst + i * 4) = *(float4*)&vals[i * 4];
  }
}

// ---------------------------------------------------------------------------
extern "C" void kernel_launch(void* const* d_in, const int* in_sizes, int n_in,
                              void* d_out, int out_size, void* d_ws, size_t ws_size,
                              hipStream_t stream) {
  (void)in_sizes; (void)n_in; (void)out_size; (void)ws_size;
  const float* x      = (const float*)d_in[0];
  const float* bn1_g  = (const float*)d_in[1];
  const float* bn1_b  = (const float*)d_in[2];
  const float* qkv_dw = (const float*)d_in[3];
  const float* qkv_pw = (const float*)d_in[4];
  const float* rel    = (const float*)d_in[5];
  const float* out_dw = (const float*)d_in[6];
  const float* out_pw = (const float*)d_in[7];
  const float* bn2_g  = (const float*)d_in[8];
  const float* bn2_b  = (const float*)d_in[9];
  const float* mlp_w  = (const float*)d_in[10];
  float* out = (float*)d_out;
  float* ws = (float*)d_ws;

  ushort* hdw16 = (ushort*)(ws + F_HDW16);
  ushort* hdwt  = (ushort*)(ws + F_HDWT);
  float*  qkv   = ws + F_QKV;
  float*  attn_o = ws + F_ATTN;
  ushort* tmp2  = (ushort*)(ws + F_TMP2);
  ushort* tmp2t = (ushort*)(ws + F_TMP2T);
  float*  y1    = ws + F_Y1;
  ushort* y1t   = (ushort*)(ws + F_Y1T);
  ushort* kdb   = (ushort*)(ws + F_KD);
  ushort* vtb   = (ushort*)(ws + F_VT);
  ushort* bias  = (ushort*)(ws + F_BIAS);
  float* sc1 = ws + F_ST, *sh1 = sc1 + 128, *sc2 = sh1 + 128, *sh2 = sc2 + 128;

  bn_stats<<<128, 256, 0, stream>>>(x, bn1_g, bn1_b, sc1, sh1);
  dwconv3<true><<<2048, 256, 0, stream>>>(x, qkv_dw, sc1, sh1, hdw16);
  transpose_cn<0><<<1024, 256, 0, stream>>>(hdw16, nullptr, nullptr, hdwt);
  gemm_mfma<false><<<dim3(256, 3), 256, 0, stream>>>(qkv_pw, hdwt, nullptr, qkv);
  downsample_kv<<<M3, 128, 0, stream>>>(qkv, kdb, vtb);
  build_bias<<<M3, 256, 0, stream>>>(rel, bias);
  attention_mfma<<<HEADS * 256, 256, 0, stream>>>(qkv, kdb, vtb, bias, attn_o);
  dwconv3<false><<<2048, 256, 0, stream>>>(attn_o, out_dw, nullptr, nullptr, tmp2);
  transpose_cn<0><<<1024, 256, 0, stream>>>(tmp2, nullptr, nullptr, tmp2t);
  gemm_mfma<true><<<dim3(256, 1), 256, 0, stream>>>(out_pw, tmp2t, x, y1);
  bn_stats<<<128, 256, 0, stream>>>(y1, bn2_g, bn2_b, sc2, sh2);
  transpose_cn<1><<<1024, 256, 0, stream>>>(y1, sc2, sh2, y1t);
  gemm_mfma<true><<<dim3(256, 1), 256, 0, stream>>>(mlp_w, y1t, y1, out);
}

// Round 12
// 257.939 us; speedup vs baseline: 1.0497x; 1.0497x over previous
//
#include <hip/hip_runtime.h>
#include <math.h>

// ---------------------------------------------------------------------------
// BasicTransBlock: BN1 -> dw3x3x3 -> pw(C->3C) -> attn(K/V downsampled to 8^3,
// rel-pos bias) -> dw3x3x3 -> pw(C->C) -> +x -> BN2 -> ReLU -> 1x1x1 -> +res
// bf16 MFMA for attention AND all pointwise GEMMs (fp32 accum everywhere).
// ---------------------------------------------------------------------------

typedef short bf16x8 __attribute__((ext_vector_type(8)));
typedef float f32x4 __attribute__((ext_vector_type(4)));
typedef unsigned short u16x8 __attribute__((ext_vector_type(8)));

constexpr int CNUM  = 128;
constexpr int NSP   = 32768;      // 32*32*32
constexpr int HEADS = 4;
constexpr int M3    = 512;        // 8^3
constexpr float EPSV  = 1e-5f;
constexpr float SCALE = 0.17677669529663688f;   // 32^-0.5
constexpr float SK    = SCALE * 1.44269504088896340736f;  // *log2(e)

// workspace layout (float slots). Aliasing audit (R6) unchanged.
constexpr size_t F_HDW16 = 0;
constexpr size_t F_HDWT  = 2097152;
constexpr size_t F_QKV   = 4194304;
constexpr size_t F_ATTN  = 0;                   // fp32 [0,4M)
constexpr size_t F_TMP2  = F_QKV;               // bf16, 2M slots
constexpr size_t F_TMP2T = F_QKV + 2097152;     // bf16, 2M slots
constexpr size_t F_Y1    = F_QKV + 4194304;     // fp32, 4M slots
constexpr size_t F_Y1T   = F_QKV + 8388608;     // bf16, 2M slots
constexpr size_t F_KD    = 16777216;            // ushort[4*512*32]  = 32768 slots
constexpr size_t F_VT    = F_KD + 32768;        // ushort[4*32*512]  = 32768 slots
constexpr size_t F_BIAS  = F_VT + 32768;        // ushort[4*512*512] = 524288 slots
constexpr size_t F_ST    = F_BIAS + 524288;     // 512 floats

__device__ inline ushort f2bf(float f) {
  unsigned u = __float_as_uint(f);
  u += 0x7fff + ((u >> 16) & 1);
  return (ushort)(u >> 16);
}
__device__ inline float bf2f(ushort u) { return __uint_as_float(((unsigned)u) << 16); }

// ---------------- BN stats: per-channel scale/shift ------------------------
__global__ __launch_bounds__(256) void bn_stats(
    const float* __restrict__ x, const float* __restrict__ g,
    const float* __restrict__ bb, float* __restrict__ scale,
    float* __restrict__ shift) {
  const int c = blockIdx.x;
  const float4* p = (const float4*)(x + (size_t)c * NSP);
  float s = 0.f, s2 = 0.f;
  for (int i = threadIdx.x; i < NSP / 4; i += 256) {
    float4 v = p[i];
    s  += v.x + v.y + v.z + v.w;
    s2 += v.x * v.x + v.y * v.y + v.z * v.z + v.w * v.w;
  }
  __shared__ float rs[4], rs2[4];
  for (int off = 32; off > 0; off >>= 1) {
    s  += __shfl_down(s, off);
    s2 += __shfl_down(s2, off);
  }
  if ((threadIdx.x & 63) == 0) { rs[threadIdx.x >> 6] = s; rs2[threadIdx.x >> 6] = s2; }
  __syncthreads();
  if (threadIdx.x == 0) {
    float S = rs[0] + rs[1] + rs[2] + rs[3];
    float S2 = rs2[0] + rs2[1] + rs2[2] + rs2[3];
    float mu = S / (float)NSP;
    float var = S2 / (float)NSP - mu * mu;
    float sc = g[c] * rsqrtf(var + EPSV);
    scale[c] = sc;
    shift[c] = bb[c] - mu * sc;
  }
}

// ---------------- depthwise 3x3x3 conv, register-blocked, bf16 out ---------
template <bool AFFINE>
__global__ __launch_bounds__(256) void dwconv3(
    const float* __restrict__ in, const float* __restrict__ w27,
    const float* __restrict__ scale, const float* __restrict__ shift,
    ushort* __restrict__ out) {
  const int idx = blockIdx.x * 256 + threadIdx.x;
  const int d0 = (idx & 3) << 3;
  const int ww = (idx >> 2) & 31;
  const int hh = (idx >> 7) & 31;
  const int c  = idx >> 12;
  const float sc = AFFINE ? scale[c] : 1.f;
  const float sh = AFFINE ? shift[c] : 0.f;
  const float* pc = in + ((size_t)c << 15);
  const float* wc = w27 + c * 27;
  float wreg[27];
#pragma unroll
  for (int k = 0; k < 27; ++k) wreg[k] = wc[k];

  float acc[8] = {};
#pragma unroll
  for (int a = 0; a < 3; ++a) {
    int h2 = hh + a - 1;
    if ((unsigned)h2 > 31u) continue;
#pragma unroll
    for (int b = 0; b < 3; ++b) {
      int w2 = ww + b - 1;
      if ((unsigned)w2 > 31u) continue;
      const float* row = pc + (h2 << 10) + (w2 << 5) + d0;
      float4 v0 = *(const float4*)(row);
      float4 v1 = *(const float4*)(row + 4);
      float win[10];
      if (AFFINE) {
        win[1] = fmaf(v0.x, sc, sh); win[2] = fmaf(v0.y, sc, sh);
        win[3] = fmaf(v0.z, sc, sh); win[4] = fmaf(v0.w, sc, sh);
        win[5] = fmaf(v1.x, sc, sh); win[6] = fmaf(v1.y, sc, sh);
        win[7] = fmaf(v1.z, sc, sh); win[8] = fmaf(v1.w, sc, sh);
        win[0] = (d0 > 0)  ? fmaf(row[-1], sc, sh) : 0.f;
        win[9] = (d0 < 24) ? fmaf(row[8],  sc, sh) : 0.f;
      } else {
        win[1] = v0.x; win[2] = v0.y; win[3] = v0.z; win[4] = v0.w;
        win[5] = v1.x; win[6] = v1.y; win[7] = v1.z; win[8] = v1.w;
        win[0] = (d0 > 0)  ? row[-1] : 0.f;
        win[9] = (d0 < 24) ? row[8]  : 0.f;
      }
      const float w0 = wreg[(a * 3 + b) * 3 + 0];
      const float w1 = wreg[(a * 3 + b) * 3 + 1];
      const float w2v = wreg[(a * 3 + b) * 3 + 2];
#pragma unroll
      for (int j = 0; j < 8; ++j)
        acc[j] += w0 * win[j] + w1 * win[j + 1] + w2v * win[j + 2];
    }
  }
  u16x8 o;
#pragma unroll
  for (int j = 0; j < 8; ++j) o[j] = f2bf(acc[j]);
  *(u16x8*)(out + ((size_t)c << 15) + (hh << 10) + (ww << 5) + d0) = o;
}

// ---------------- transpose [c][n] -> [n][c] bf16 (64x64 LDS tiles) --------
template <int MODE>
__global__ __launch_bounds__(256) void transpose_cn(
    const void* __restrict__ inp, const float* __restrict__ sc_,
    const float* __restrict__ sh_, ushort* __restrict__ outp) {
  __shared__ ushort T[64][72];
  const int tid = threadIdx.x;
  const int c0 = (blockIdx.x & 1) << 6;
  const int n0 = (blockIdx.x >> 1) << 6;
  const int r = tid >> 2, q = (tid & 3) << 4;
  if (MODE == 0) {
    const ushort* src = (const ushort*)inp + (size_t)(c0 + r) * NSP + n0 + q;
    *(u16x8*)&T[r][q]     = *(const u16x8*)src;
    *(u16x8*)&T[r][q + 8] = *(const u16x8*)(src + 8);
  } else {
    const float* src = (const float*)inp + (size_t)(c0 + r) * NSP + n0 + q;
    const float s = sc_[c0 + r], h = sh_[c0 + r];
    float4 v0 = ((const float4*)src)[0], v1 = ((const float4*)src)[1];
    float4 v2 = ((const float4*)src)[2], v3 = ((const float4*)src)[3];
    u16x8 a, b;
    a[0] = f2bf(fmaxf(fmaf(v0.x, s, h), 0.f));
    a[1] = f2bf(fmaxf(fmaf(v0.y, s, h), 0.f));
    a[2] = f2bf(fmaxf(fmaf(v0.z, s, h), 0.f));
    a[3] = f2bf(fmaxf(fmaf(v0.w, s, h), 0.f));
    a[4] = f2bf(fmaxf(fmaf(v1.x, s, h), 0.f));
    a[5] = f2bf(fmaxf(fmaf(v1.y, s, h), 0.f));
    a[6] = f2bf(fmaxf(fmaf(v1.z, s, h), 0.f));
    a[7] = f2bf(fmaxf(fmaf(v1.w, s, h), 0.f));
    b[0] = f2bf(fmaxf(fmaf(v2.x, s, h), 0.f));
    b[1] = f2bf(fmaxf(fmaf(v2.y, s, h), 0.f));
    b[2] = f2bf(fmaxf(fmaf(v2.z, s, h), 0.f));
    b[3] = f2bf(fmaxf(fmaf(v2.w, s, h), 0.f));
    b[4] = f2bf(fmaxf(fmaf(v3.x, s, h), 0.f));
    b[5] = f2bf(fmaxf(fmaf(v3.y, s, h), 0.f));
    b[6] = f2bf(fmaxf(fmaf(v3.z, s, h), 0.f));
    b[7] = f2bf(fmaxf(fmaf(v3.w, s, h), 0.f));
    *(u16x8*)&T[r][q]     = a;
    *(u16x8*)&T[r][q + 8] = b;
  }
  __syncthreads();
  const int rn = tid >> 2, cq = (tid & 3) << 4;
  u16x8 o0, o1;
#pragma unroll
  for (int j = 0; j < 8; ++j) { o0[j] = T[cq + j][rn]; o1[j] = T[cq + 8 + j][rn]; }
  ushort* dst = outp + (size_t)(n0 + rn) * 128 + c0 + cq;
  *(u16x8*)dst       = o0;
  *(u16x8*)(dst + 8) = o1;
}

// ---------------- bf16 MFMA GEMM (unchanged from R6) -----------------------
template <bool RES>
__global__ __launch_bounds__(256) void gemm_mfma(
    const float* __restrict__ W, const ushort* __restrict__ Bt,
    const float* __restrict__ res, float* __restrict__ out) {
  __shared__ ushort Wl[128][40];
  __shared__ ushort Bl[128][40];
  const int tid = threadIdx.x;
  const int lane = tid & 63, w = tid >> 6;
  const int g = lane >> 4, c = lane & 15;
  const int n0 = blockIdx.x << 7, oc0 = blockIdx.y << 7;
  const int wr = (w >> 1) << 6, wc = (w & 1) << 6;
  f32x4 acc[4][4];
#pragma unroll
  for (int mt = 0; mt < 4; ++mt)
#pragma unroll
    for (int nt = 0; nt < 4; ++nt) acc[mt][nt] = {0.f, 0.f, 0.f, 0.f};
  const int sr = tid >> 1, sh2 = (tid & 1) << 4;
  for (int k0 = 0; k0 < 128; k0 += 32) {
    __syncthreads();
    {
      const float* wsrc = W + (size_t)(oc0 + sr) * 128 + k0 + sh2;
      float4 a = ((const float4*)wsrc)[0];
      float4 b = ((const float4*)wsrc)[1];
      float4 cc = ((const float4*)wsrc)[2];
      float4 dd = ((const float4*)wsrc)[3];
      u16x8 p0, p1;
      p0[0] = f2bf(a.x);  p0[1] = f2bf(a.y);  p0[2] = f2bf(a.z);  p0[3] = f2bf(a.w);
      p0[4] = f2bf(b.x);  p0[5] = f2bf(b.y);  p0[6] = f2bf(b.z);  p0[7] = f2bf(b.w);
      p1[0] = f2bf(cc.x); p1[1] = f2bf(cc.y); p1[2] = f2bf(cc.z); p1[3] = f2bf(cc.w);
      p1[4] = f2bf(dd.x); p1[5] = f2bf(dd.y); p1[6] = f2bf(dd.z); p1[7] = f2bf(dd.w);
      *(u16x8*)&Wl[sr][sh2]     = p0;
      *(u16x8*)&Wl[sr][sh2 + 8] = p1;
      const ushort* bsrc = Bt + (size_t)(n0 + sr) * 128 + k0 + sh2;
      *(u16x8*)&Bl[sr][sh2]     = *(const u16x8*)bsrc;
      *(u16x8*)&Bl[sr][sh2 + 8] = *(const u16x8*)(bsrc + 8);
    }
    __syncthreads();
    bf16x8 af[4], bfr[4];
#pragma unroll
    for (int mt = 0; mt < 4; ++mt)
      af[mt] = *(const bf16x8*)&Wl[wr + mt * 16 + c][g * 8];
#pragma unroll
    for (int nt = 0; nt < 4; ++nt)
      bfr[nt] = *(const bf16x8*)&Bl[wc + nt * 16 + c][g * 8];
#pragma unroll
    for (int mt = 0; mt < 4; ++mt)
#pragma unroll
      for (int nt = 0; nt < 4; ++nt)
        acc[mt][nt] = __builtin_amdgcn_mfma_f32_16x16x32_bf16(
            af[mt], bfr[nt], acc[mt][nt], 0, 0, 0);
  }
#pragma unroll
  for (int mt = 0; mt < 4; ++mt) {
#pragma unroll
    for (int nt = 0; nt < 4; ++nt) {
      const int n = n0 + wc + nt * 16 + c;
#pragma unroll
      for (int r = 0; r < 4; ++r) {
        const int oc = oc0 + wr + mt * 16 + g * 4 + r;
        size_t off = (size_t)oc * NSP + n;
        float o = acc[mt][nt][r];
        if (RES) o += res[off];
        out[off] = o;
      }
    }
  }
}

// ---------------- trilinear downsample of k,v to 8^3 (bf16 out) ------------
__device__ inline void interp8(int p, int& lo, float& w) {
  double pos = (double)p * 31.0 / 7.0;
  int l = (int)pos;
  if (l > 30) l = 30;
  lo = l;
  w = (float)(pos - (double)l);
}

__global__ __launch_bounds__(128) void downsample_kv(
    const float* __restrict__ qkv, ushort* __restrict__ kd,
    ushort* __restrict__ vt) {
  const int m = blockIdx.x, c = threadIdx.x;
  const int p = m >> 6, q = (m >> 3) & 7, r = m & 7;
  int lp, lq, lr; float wp, wq, wr;
  interp8(p, lp, wp); interp8(q, lq, wq); interp8(r, lr, wr);
  const float* kp = qkv + (size_t)(CNUM + c) * NSP;
  const float* vp = qkv + (size_t)(2 * CNUM + c) * NSP;
  float ak = 0.f, av = 0.f;
#pragma unroll
  for (int a = 0; a < 2; ++a)
#pragma unroll
    for (int b = 0; b < 2; ++b)
#pragma unroll
      for (int e = 0; e < 2; ++e) {
        float wgt = (a ? wp : 1.f - wp) * (b ? wq : 1.f - wq) * (e ? wr : 1.f - wr);
        int off = ((lp + a) << 10) + ((lq + b) << 5) + (lr + e);
        ak = fmaf(wgt, kp[off], ak);
        av = fmaf(wgt, vp[off], av);
      }
  const int d = c >> 2, h = c & 3;
  kd[((size_t)(h * M3 + m)) * 32 + d] = f2bf(ak);       // K: [h][m][d]
  vt[((size_t)(h * 32 + d)) * M3 + m] = f2bf(av);       // V^T: [h][d][m]
}

// ---------------- relative position bias table [4][512][512] bf16 ----------
// R8 change: PRE-SCALED by SK so attention's inner loop is a single fma.
__global__ __launch_bounds__(256) void build_bias(
    const float* __restrict__ rel, ushort* __restrict__ biasmat) {
  const int nr = blockIdx.x;
  const int p0 = nr >> 6, q0 = (nr >> 3) & 7, r0 = nr & 7;
  for (int m = threadIdx.x; m < M3; m += 256) {
    int p1 = m >> 6, q1 = (m >> 3) & 7, r1 = m & 7;
    int idx = (p0 - p1 + 7) * 15 + (q0 - q1 + 7) + (r0 - r1);
    if (idx < 0) idx += 3375;  // torch-style negative wrap
#pragma unroll
    for (int h = 0; h < 4; ++h)
      biasmat[((size_t)(h * M3 + nr)) * M3 + m] = f2bf(rel[idx * 4 + h] * SK);
  }
}

// ---------------- attention: bf16 MFMA, swapped QK^T, online softmax -------
// R11 post-mortem: launch_bounds(256,4) + st[2][8] (64 VGPR live) forced
// spills -> 83MB scratch writes, attention got SLOWER. R12: per-s
// processing (st[8] only, QK re-reads K frags from LDS - cheap) and
// launch_bounds(256,3); actual usage ~<=128 VGPR lets HW reach 4 blk/CU
// without forcing the allocator to spill.
__global__ __launch_bounds__(256, 3) void attention_mfma(
    const float* __restrict__ q, const ushort* __restrict__ kd,
    const ushort* __restrict__ vt, const ushort* __restrict__ biasg,
    float* __restrict__ attn_out) {
  __shared__ ushort lds[16192];
  ushort* Kl = lds;                      // [128][40]
  ushort* Vl = lds + 5120;               // [32][136]
  ushort* Bl = lds + 9472;               // [8][520]  (pre-scaled bias)
  ushort* Pl = lds + 13632;              // 4 waves x [16][40]
  const int tid = threadIdx.x;
  const int lane = tid & 63, w = tid >> 6;
  const int g = lane >> 4, c = lane & 15;
  const int head = blockIdx.x >> 8;
  const int n0 = (blockIdx.x & 255) << 7;

  {  // stage the 8 bias rows (nr varies only in d/4 within this block)
    int nr_base = ((n0 >> 12) << 6) + ((((n0 >> 5) & 31) >> 2) << 3);
    int row = tid >> 5, col = (tid & 31) << 4;
    const float4* src =
        (const float4*)(biasg + ((size_t)(head * M3 + nr_base + row)) * M3 + col);
    *(float4*)&Bl[row * 520 + col] = src[0];
    *(float4*)&Bl[row * 520 + col + 8] = src[1];
  }

  bf16x8 qf[2];
#pragma unroll
  for (int s = 0; s < 2; ++s) {
    int n = n0 + w * 32 + s * 16 + c;
#pragma unroll
    for (int j = 0; j < 8; ++j)
      qf[s][j] = (short)f2bf(q[(size_t)((g * 8 + j) * 4 + head) * NSP + n]);
  }

  f32x4 acc[2][2];
#pragma unroll
  for (int s = 0; s < 2; ++s)
#pragma unroll
    for (int dt = 0; dt < 2; ++dt) acc[s][dt] = {0.f, 0.f, 0.f, 0.f};
  float rmax[2] = {-1e30f, -1e30f};
  float rsum[2] = {0.f, 0.f};
  ushort* Pw = Pl + w * 640;             // [16][40] per wave
  const f32x4 zero4 = {0.f, 0.f, 0.f, 0.f};

  for (int mt = 0; mt < M3; mt += 128) {
    __syncthreads();
    {  // stage K [128][32]->[128][40]; V^T [32][128]->[32][136]
      int r = tid >> 1, hp = (tid & 1) << 4;
      const float4* ksrc =
          (const float4*)(kd + ((size_t)(head * M3 + mt + r)) * 32 + hp);
      *(float4*)&Kl[r * 40 + hp] = ksrc[0];
      *(float4*)&Kl[r * 40 + hp + 8] = ksrc[1];
      int d = tid >> 3, mc = (tid & 7) << 4;
      const float4* vs = (const float4*)(vt + ((size_t)(head * 32 + d)) * M3 + mt + mc);
      *(float4*)&Vl[d * 136 + mc] = vs[0];
      *(float4*)&Vl[d * 136 + mc + 8] = vs[1];
    }
    __syncthreads();
    // Per sub-block s: QK MFMA, bias+max, exp+pack+PV. Only st[8] live.
#pragma unroll
    for (int s = 0; s < 2; ++s) {
      f32x4 st[8];
      __builtin_amdgcn_s_setprio(1);
#pragma unroll
      for (int t = 0; t < 8; ++t) {
        bf16x8 kf = *(const bf16x8*)&Kl[(t * 16 + c) * 40 + g * 8];
        st[t] = __builtin_amdgcn_mfma_f32_16x16x32_bf16(kf, qf[s], zero4, 0, 0, 0);
      }
      __builtin_amdgcn_s_setprio(0);
      const int brow = s * 4 + (c >> 2);
      float mx = -1e30f;
#pragma unroll
      for (int t = 0; t < 8; ++t) {
        ushort4 bb = *(const ushort4*)&Bl[brow * 520 + mt + t * 16 + g * 4];
        st[t][0] = fmaf(st[t][0], SK, bf2f(bb.x));
        st[t][1] = fmaf(st[t][1], SK, bf2f(bb.y));
        st[t][2] = fmaf(st[t][2], SK, bf2f(bb.z));
        st[t][3] = fmaf(st[t][3], SK, bf2f(bb.w));
        mx = fmaxf(mx, fmaxf(fmaxf(st[t][0], st[t][1]),
                             fmaxf(st[t][2], st[t][3])));
      }
      mx = fmaxf(mx, __shfl_xor(mx, 16));
      mx = fmaxf(mx, __shfl_xor(mx, 32));
      float mnew = fmaxf(rmax[s], mx);
      float f = exp2f(rmax[s] - mnew);
      rmax[s] = mnew;
      float fr0 = __shfl(f, g * 4 + 0), fr1 = __shfl(f, g * 4 + 1);
      float fr2 = __shfl(f, g * 4 + 2), fr3 = __shfl(f, g * 4 + 3);
#pragma unroll
      for (int dt = 0; dt < 2; ++dt) {
        acc[s][dt][0] *= fr0; acc[s][dt][1] *= fr1;
        acc[s][dt][2] *= fr2; acc[s][dt][3] *= fr3;
      }
      float psum = 0.f;
#pragma unroll
      for (int ks = 0; ks < 4; ++ks) {
        // exp + pack 2 column-groups (32 keys), then PV that slice.
#pragma unroll
        for (int dt2 = 0; dt2 < 2; ++dt2) {
          const int t = ks * 2 + dt2;
          float p0 = exp2f(st[t][0] - mnew);
          float p1 = exp2f(st[t][1] - mnew);
          float p2 = exp2f(st[t][2] - mnew);
          float p3 = exp2f(st[t][3] - mnew);
          psum += (p0 + p1) + (p2 + p3);
          unsigned lo, hi;
          asm("v_cvt_pk_bf16_f32 %0, %1, %2" : "=v"(lo) : "v"(p0), "v"(p1));
          asm("v_cvt_pk_bf16_f32 %0, %1, %2" : "=v"(hi) : "v"(p2), "v"(p3));
          uint2 pk; pk.x = lo; pk.y = hi;
          *(uint2*)&Pw[c * 40 + dt2 * 16 + g * 4] = pk;
        }
        // same-wave DS ops are ordered: read back the slice as A-fragment
        bf16x8 pa = *(const bf16x8*)&Pw[c * 40 + g * 8];
        __builtin_amdgcn_s_setprio(1);
#pragma unroll
        for (int dt = 0; dt < 2; ++dt) {
          bf16x8 vb = *(const bf16x8*)&Vl[(dt * 16 + c) * 136 + ks * 32 + g * 8];
          acc[s][dt] = __builtin_amdgcn_mfma_f32_16x16x32_bf16(pa, vb, acc[s][dt], 0, 0, 0);
        }
        __builtin_amdgcn_s_setprio(0);
      }
      psum += __shfl_xor(psum, 16);
      psum += __shfl_xor(psum, 32);
      rsum[s] = rsum[s] * f + psum;
    }
  }
  __syncthreads();              // K/V/bias dead; reuse lds as Ol [128][33] f32
  float* Ol = (float*)lds;
#pragma unroll
  for (int s = 0; s < 2; ++s) {
    float inv = 1.f / rsum[s];
#pragma unroll
    for (int r = 0; r < 4; ++r) {
      float fr = __shfl(inv, g * 4 + r);
      int row = w * 32 + s * 16 + g * 4 + r;
#pragma unroll
      for (int dt = 0; dt < 2; ++dt)
        Ol[row * 33 + dt * 16 + c] = acc[s][dt][r] * fr;
    }
  }
  __syncthreads();
  {
    int d = tid >> 3, seg = tid & 7;
    float vals[16];
#pragma unroll
    for (int i = 0; i < 16; ++i) vals[i] = Ol[(seg * 16 + i) * 33 + d];
    float* dst = attn_out + (size_t)(d * 4 + head) * NSP + n0 + seg * 16;
#pragma unroll
    for (int i = 0; i < 4; ++i) *(float4*)(dst + i * 4) = *(float4*)&vals[i * 4];
  }
}

// ---------------------------------------------------------------------------
extern "C" void kernel_launch(void* const* d_in, const int* in_sizes, int n_in,
                              void* d_out, int out_size, void* d_ws, size_t ws_size,
                              hipStream_t stream) {
  (void)in_sizes; (void)n_in; (void)out_size; (void)ws_size;
  const float* x      = (const float*)d_in[0];
  const float* bn1_g  = (const float*)d_in[1];
  const float* bn1_b  = (const float*)d_in[2];
  const float* qkv_dw = (const float*)d_in[3];
  const float* qkv_pw = (const float*)d_in[4];
  const float* rel    = (const float*)d_in[5];
  const float* out_dw = (const float*)d_in[6];
  const float* out_pw = (const float*)d_in[7];
  const float* bn2_g  = (const float*)d_in[8];
  const float* bn2_b  = (const float*)d_in[9];
  const float* mlp_w  = (const float*)d_in[10];
  float* out = (float*)d_out;
  float* ws = (float*)d_ws;

  ushort* hdw16 = (ushort*)(ws + F_HDW16);
  ushort* hdwt  = (ushort*)(ws + F_HDWT);
  float*  qkv   = ws + F_QKV;
  float*  attn_o = ws + F_ATTN;
  ushort* tmp2  = (ushort*)(ws + F_TMP2);
  ushort* tmp2t = (ushort*)(ws + F_TMP2T);
  float*  y1    = ws + F_Y1;
  ushort* y1t   = (ushort*)(ws + F_Y1T);
  ushort* kdb   = (ushort*)(ws + F_KD);
  ushort* vtb   = (ushort*)(ws + F_VT);
  ushort* bias  = (ushort*)(ws + F_BIAS);
  float* sc1 = ws + F_ST, *sh1 = sc1 + 128, *sc2 = sh1 + 128, *sh2 = sc2 + 128;

  bn_stats<<<128, 256, 0, stream>>>(x, bn1_g, bn1_b, sc1, sh1);
  dwconv3<true><<<2048, 256, 0, stream>>>(x, qkv_dw, sc1, sh1, hdw16);
  transpose_cn<0><<<1024, 256, 0, stream>>>(hdw16, nullptr, nullptr, hdwt);
  gemm_mfma<false><<<dim3(256, 3), 256, 0, stream>>>(qkv_pw, hdwt, nullptr, qkv);
  downsample_kv<<<M3, 128, 0, stream>>>(qkv, kdb, vtb);
  build_bias<<<M3, 256, 0, stream>>>(rel, bias);
  attention_mfma<<<HEADS * 256, 256, 0, stream>>>(qkv, kdb, vtb, bias, attn_o);
  dwconv3<false><<<2048, 256, 0, stream>>>(attn_o, out_dw, nullptr, nullptr, tmp2);
  transpose_cn<0><<<1024, 256, 0, stream>>>(tmp2, nullptr, nullptr, tmp2t);
  gemm_mfma<true><<<dim3(256, 1), 256, 0, stream>>>(out_pw, tmp2t, x, y1);
  bn_stats<<<128, 256, 0, stream>>>(y1, bn2_g, bn2_b, sc2, sh2);
  transpose_cn<1><<<1024, 256, 0, stream>>>(y1, sc2, sh2, y1t);
  gemm_mfma<true><<<dim3(256, 1), 256, 0, stream>>>(mlp_w, y1t, y1, out);
}